// Round 9
// baseline (732.770 us; speedup 1.0000x reference)
//
#include <hip/hip_runtime.h>
#include <hip/hip_cooperative_groups.h>
#include <cstddef>

namespace {
constexpr int B_     = 128;
constexpr int HW     = 65536;        // 256*256
constexpr int EMB_   = 64;
constexpr int NF     = EMB_ + 18;    // 82
constexpr int BNF    = B_ * NF;      // 10496 ([n][m] layout)
constexpr int CHUNKS = 512;          // k-chunks for split-K reduce (2 per block)
constexpr int WPITCH = 40;           // W tile row pitch in bf16 (32 + 8 pad)
constexpr int IPITCH = 260;          // LDS image row pitch in bf16
constexpr int ARENA_BYTES = 256 * IPITCH * 2;  // 133120
}

typedef short  s16x4 __attribute__((ext_vector_type(4)));
typedef float  f32x4 __attribute__((ext_vector_type(4)));

__device__ __forceinline__ unsigned short bf16rn(float f) {
    unsigned u = __float_as_uint(f);
    u += 0x7FFFu + ((u >> 16) & 1u);
    return (unsigned short)(u >> 16);
}
__device__ __forceinline__ float bf16tof(unsigned short h) {
    return __uint_as_float(((unsigned)h) << 16);
}

// ---------- grid-sample phase: full source image in LDS, taps on LDS pipe ----
template <bool F32OUT>
__device__ __forceinline__ void gs_phase(
    const unsigned short* __restrict__ src, void* __restrict__ dst,
    const float* __restrict__ featsT, int theta_sel, unsigned short* simg)
{
    const int p    = blockIdx.x;
    const int b    = ((p >> 4) << 3) | (p & 7);   // pair halves onto one image/XCD
    const int half = (p >> 3) & 1;
    const int tid  = threadIdx.x;

    const unsigned short* __restrict__ sb = src + ((size_t)b << 16);
    const ushort4* __restrict__ s4 = reinterpret_cast<const ushort4*>(sb);
#pragma unroll
    for (int it = 0; it < 16; ++it) {
        const int i  = tid + (it << 10);
        const int r  = i >> 6;
        const int c4 = i & 63;
        *reinterpret_cast<ushort4*>(&simg[r * IPITCH + (c4 << 2)]) = s4[i];
    }

    const int tb = EMB_ + theta_sel * 6;
    const float t00 = featsT[(size_t)(tb + 0) * B_ + b];
    const float t01 = featsT[(size_t)(tb + 1) * B_ + b];
    const float t02 = featsT[(size_t)(tb + 2) * B_ + b];
    const float t10 = featsT[(size_t)(tb + 3) * B_ + b];
    const float t11 = featsT[(size_t)(tb + 4) * B_ + b];
    const float t12 = featsT[(size_t)(tb + 5) * B_ + b];

    __syncthreads();

#pragma unroll 2
    for (int it = 0; it < 32; ++it) {
        const int px = (it << 10) + tid;      // 0..32767 within half
        const int y  = (half << 7) + (px >> 8);
        const int xq = px & 255;

        const float X = (float)(2 * xq + 1) * (1.f / 256.f) - 1.f;
        const float Y = (float)(2 * y  + 1) * (1.f / 256.f) - 1.f;

        const float gx = t00 * X + t01 * Y + t02;
        const float gy = t10 * X + t11 * Y + t12;

        const float ix = (gx + 1.f) * 128.f - 0.5f;
        const float iy = (gy + 1.f) * 128.f - 0.5f;
        const float ix0 = floorf(ix);
        const float iy0 = floorf(iy);
        const float wx1 = ix - ix0, wx0 = 1.f - wx1;
        const float wy1 = iy - iy0, wy0 = 1.f - wy1;

        auto tap = [&](float xf, float yf) -> float {
            const bool valid = (xf >= 0.f) && (xf < 256.f) &&
                               (yf >= 0.f) && (yf < 256.f);
            const int xi = (int)fminf(fmaxf(xf, 0.f), 255.f);
            const int yi = (int)fminf(fmaxf(yf, 0.f), 255.f);
            const float v = bf16tof(simg[yi * IPITCH + xi]);
            return valid ? v : 0.f;
        };
        const float v00 = tap(ix0,       iy0);
        const float v10 = tap(ix0 + 1.f, iy0);
        const float v01 = tap(ix0,       iy0 + 1.f);
        const float v11 = tap(ix0 + 1.f, iy0 + 1.f);

        const float r = v00 * (wx0 * wy0) + v10 * (wx1 * wy0) +
                        v01 * (wx0 * wy1) + v11 * (wx1 * wy1);
        const size_t di = ((size_t)b << 16) + ((size_t)half << 15) + px;
        if (F32OUT) ((float*)dst)[di] = r;
        else        ((unsigned short*)dst)[di] = bf16rn(r);
    }
}

// =================== cooperative mega-kernel: all 6 phases ===================
__global__ __launch_bounds__(1024, 4) void mega_k(
    const float* __restrict__ x, const float* __restrict__ Wenc,
    const float* __restrict__ benc, const float* __restrict__ Wdec,
    const float* __restrict__ bdec, float* __restrict__ out,
    float* __restrict__ partialT, float* __restrict__ featsT,
    unsigned short* __restrict__ imgB0, unsigned short* __restrict__ imgB1,
    unsigned short* __restrict__ imgB2)
{
    extern __shared__ __align__(16) unsigned char arena[];
    cooperative_groups::grid_group grid = cooperative_groups::this_grid();
    const int tid = threadIdx.x;

    // ---------------- P1: encoder split-K bf16 MFMA ----------------
    // 16 waves: kh = wv>>3 selects 128-k half-chunk, wv&7 selects m-subtile.
    {
        const int lane = tid & 63;
        const int wv   = tid >> 6;          // 0..15
        const int kh   = wv >> 3;
        const int ln15 = lane & 15;
        const int lg   = lane >> 4;
        const int m0   = (wv & 7) << 4;
        const int kbase = blockIdx.x * 256 + kh * 128;
        unsigned short* wH = (unsigned short*)arena + kh * 7680;
        unsigned short* wL = wH + 3840;
        const int gtid = tid & 511;
        const float* __restrict__ xrow = x + (size_t)(m0 + ln15) * HW + kbase;

        f32x4 acc[6];
#pragma unroll
        for (int t = 0; t < 6; ++t) acc[t] = (f32x4){0.f, 0.f, 0.f, 0.f};

        float4 xa = *reinterpret_cast<const float4*>(&xrow[lg * 4]);
        float4 xb = *reinterpret_cast<const float4*>(&xrow[16 + lg * 4]);

        for (int step = 0; step < 4; ++step) {
            __syncthreads();
            {   // each 512-thread group stages its own half-chunk's W tile
                const float4* wsrc = reinterpret_cast<const float4*>(
                    Wenc + (size_t)(kbase + step * 32) * NF);
                for (int i4 = gtid; i4 < (32 * NF) / 4; i4 += 512) {
                    const float4 w4 = wsrc[i4];
                    const float wv4[4] = {w4.x, w4.y, w4.z, w4.w};
#pragma unroll
                    for (int j = 0; j < 4; ++j) {
                        const int idx = i4 * 4 + j;
                        const int kk  = idx / NF;
                        const int n   = idx - kk * NF;
                        const unsigned short hi = bf16rn(wv4[j]);
                        wH[n * WPITCH + kk] = hi;
                        wL[n * WPITCH + kk] = bf16rn(wv4[j] - bf16tof(hi));
                    }
                }
            }
            float4 xa1, xb1;
            if (step < 3) {
                xa1 = *reinterpret_cast<const float4*>(&xrow[(step + 1) * 32 + lg * 4]);
                xb1 = *reinterpret_cast<const float4*>(&xrow[(step + 1) * 32 + 16 + lg * 4]);
            }
            __syncthreads();

            s16x4 bh[2], bl[2];
            {
                const float xv[8] = {xa.x, xa.y, xa.z, xa.w, xb.x, xb.y, xb.z, xb.w};
#pragma unroll
                for (int s = 0; s < 2; ++s)
#pragma unroll
                    for (int j = 0; j < 4; ++j) {
                        const float v = xv[s * 4 + j];
                        const unsigned short hi = bf16rn(v);
                        bh[s][j] = (short)hi;
                        bl[s][j] = (short)bf16rn(v - bf16tof(hi));
                    }
            }

#pragma unroll
            for (int s = 0; s < 2; ++s) {
#pragma unroll
                for (int t = 0; t < 6; ++t) {
                    const int aoff = (t * 16 + ln15) * WPITCH + s * 16 + lg * 4;
                    const s16x4 ah = *reinterpret_cast<const s16x4*>(&wH[aoff]);
                    acc[t] = __builtin_amdgcn_mfma_f32_16x16x16bf16_1k(
                        ah, bh[s], acc[t], 0, 0, 0);
                    if (t >= 4) {   // theta tiles: 3-term bf16 split
                        const s16x4 al = *reinterpret_cast<const s16x4*>(&wL[aoff]);
                        acc[t] = __builtin_amdgcn_mfma_f32_16x16x16bf16_1k(
                            ah, bl[s], acc[t], 0, 0, 0);
                        acc[t] = __builtin_amdgcn_mfma_f32_16x16x16bf16_1k(
                            al, bh[s], acc[t], 0, 0, 0);
                    }
                }
            }
            if (step < 3) { xa = xa1; xb = xb1; }
        }

        float* __restrict__ base =
            partialT + (size_t)(blockIdx.x * 2 + kh) * BNF;
#pragma unroll
        for (int t = 0; t < 5; ++t)
#pragma unroll
            for (int r = 0; r < 4; ++r) {
                const int n = t * 16 + lg * 4 + r;
                base[(size_t)n * B_ + m0 + ln15] = acc[t][r];
            }
        if (lg == 0) {
#pragma unroll
            for (int r = 0; r < 2; ++r)
                base[(size_t)(80 + r) * B_ + m0 + ln15] = acc[5][r];
        }
    }
    __threadfence();
    grid.sync();

    // ---------------- P2: reduce 512 chunks -> featsT (+bias) ----------------
    if (blockIdx.x < NF) {
        float* red = (float*)arena;          // [8][128]
        const int n = blockIdx.x;
        const int m = tid & 127;
        const int g = tid >> 7;              // 0..7
        const float* p = partialT + (size_t)(g * 64) * BNF + (size_t)n * B_ + m;
        float s = 0.f;
#pragma unroll 8
        for (int c = 0; c < 64; ++c) s += p[(size_t)c * BNF];
        red[g * 128 + m] = s;
        __syncthreads();
        if (g == 0) {
            float t = benc[n];
#pragma unroll
            for (int j = 0; j < 8; ++j) t += red[j * 128 + m];
            featsT[(size_t)n * B_ + m] = t;
        }
    }
    __threadfence();
    grid.sync();

    // ---------------- P3: decoder GEMM (bf16 out) ----------------
    // 256 blocks x 256-col tiles; thread tile 8m x 4p; Wdec read once.
    {
        float* embT = (float*)arena;         // 32 KB, [k*128+m]
        for (int i = tid; i < EMB_ * B_; i += 1024) embT[i] = featsT[i];
        __syncthreads();

        const int tp = tid & 63;
        const int tm = tid >> 6;             // 0..15
        const int p0 = blockIdx.x * 256 + tp * 4;
        const int m0 = tm * 8;

        float acc[8][4];
#pragma unroll
        for (int i = 0; i < 8; ++i)
#pragma unroll
            for (int q = 0; q < 4; ++q) acc[i][q] = 0.f;

#pragma unroll 4
        for (int k = 0; k < EMB_; ++k) {
            const float4 w  = *reinterpret_cast<const float4*>(&Wdec[(size_t)k * HW + p0]);
            const float4 e0 = *reinterpret_cast<const float4*>(&embT[k * B_ + m0]);
            const float4 e1 = *reinterpret_cast<const float4*>(&embT[k * B_ + m0 + 4]);
            const float ev[8] = {e0.x, e0.y, e0.z, e0.w, e1.x, e1.y, e1.z, e1.w};
#pragma unroll
            for (int i = 0; i < 8; ++i) {
                acc[i][0] = fmaf(ev[i], w.x, acc[i][0]);
                acc[i][1] = fmaf(ev[i], w.y, acc[i][1]);
                acc[i][2] = fmaf(ev[i], w.z, acc[i][2]);
                acc[i][3] = fmaf(ev[i], w.w, acc[i][3]);
            }
        }
        const float4 bd = *reinterpret_cast<const float4*>(&bdec[p0]);
#pragma unroll
        for (int i = 0; i < 8; ++i) {
            ushort4 o;
            o.x = bf16rn(acc[i][0] + bd.x);
            o.y = bf16rn(acc[i][1] + bd.y);
            o.z = bf16rn(acc[i][2] + bd.z);
            o.w = bf16rn(acc[i][3] + bd.w);
            *reinterpret_cast<ushort4*>(&imgB0[((size_t)(m0 + i) << 16) + p0]) = o;
        }
    }
    __threadfence();
    grid.sync();

    // ---------------- P4-P6: chained grid-samples ----------------
    unsigned short* simg = (unsigned short*)arena;
    // reference order: grid_3 (translation=2), grid_1 (scaler_shear=0), grid_2 (rotation=1)
    gs_phase<false>(imgB0, imgB1, featsT, 2, simg);
    __threadfence();
    grid.sync();
    gs_phase<false>(imgB1, imgB2, featsT, 0, simg);
    __threadfence();
    grid.sync();
    gs_phase<true>(imgB2, out, featsT, 1, simg);
}

extern "C" void kernel_launch(void* const* d_in, const int* in_sizes, int n_in,
                              void* d_out, int out_size, void* d_ws, size_t ws_size,
                              hipStream_t stream)
{
    const float* x    = (const float*)d_in[0];
    const float* Wenc = (const float*)d_in[1];
    const float* benc = (const float*)d_in[2];
    const float* Wdec = (const float*)d_in[3];
    const float* bdec = (const float*)d_in[4];
    float* out = (float*)d_out;

    // strict fresh-address discipline: no buffer is read after being rewritten
    char* wsb = (char*)d_ws;
    float* partialT       = (float*)wsb;                           // 21.5 MB
    float* featsT         = (float*)(wsb + ((size_t)22 << 20));    // 41 KB
    unsigned short* imgB0 = (unsigned short*)(wsb + ((size_t)24 << 20)); // 16.8 MB
    unsigned short* imgB1 = (unsigned short*)(wsb + ((size_t)48 << 20)); // 16.8 MB
    unsigned short* imgB2 = (unsigned short*)(wsb + ((size_t)72 << 20)); // 16.8 MB

    (void)hipFuncSetAttribute((const void*)mega_k,
        hipFuncAttributeMaxDynamicSharedMemorySize, ARENA_BYTES);

    void* args[] = {
        (void*)&x, (void*)&Wenc, (void*)&benc, (void*)&Wdec, (void*)&bdec,
        (void*)&out, (void*)&partialT, (void*)&featsT,
        (void*)&imgB0, (void*)&imgB1, (void*)&imgB2,
    };
    (void)hipLaunchCooperativeKernel((const void*)mega_k, dim3(256), dim3(1024),
                                     args, ARENA_BYTES, stream);
}

// Round 10
// 147.916 us; speedup vs baseline: 4.9539x; 4.9539x over previous
//
#include <hip/hip_runtime.h>
#include <cstddef>

namespace {
constexpr int B_   = 128;
constexpr int HW   = 65536;        // 256*256
constexpr int EMB_ = 64;
constexpr int NF   = EMB_ + 18;    // 82
constexpr int BNF  = B_ * NF;      // 10496  ([n][m] layout)
constexpr int KCH  = 256;          // k-chunks (encoder grid)
constexpr int KC   = HW / KCH;     // 256 k per block
constexpr int NSTEP = KC / 32;     // 8 steps of 32 k
constexpr int WPITCH = 40;         // W tile row pitch in bf16 (32 + 8 pad)
constexpr int IPITCH = 260;        // LDS image row pitch in bf16
// padded image: 4-short front slack + 260 rows (image at rows 2..257, cols 0..255;
// rows 0,1,258,259 and cols 256..259 zeroed -> taps need no validity logic)
constexpr int SIMG_SHORTS = 4 + 260 * IPITCH;
constexpr size_t GS_LDS = (size_t)SIMG_SHORTS * 2 + 8;   // 135216 B
}

typedef short  s16x4 __attribute__((ext_vector_type(4)));
typedef float  f32x4 __attribute__((ext_vector_type(4)));

__device__ __forceinline__ unsigned short bf16rn(float f) {
    unsigned u = __float_as_uint(f);
    u += 0x7FFFu + ((u >> 16) & 1u);
    return (unsigned short)(u >> 16);
}
__device__ __forceinline__ float bf16tof(unsigned short h) {
    return __uint_as_float(((unsigned)h) << 16);
}
__device__ __forceinline__ void stpix(unsigned short* p, float v) { *p = bf16rn(v); }
__device__ __forceinline__ void stpix(float* p, float v)          { *p = v; }

// ---------------- Encoder: split-K bf16 MFMA ----------------
__global__ __launch_bounds__(512) void enc_mfma_k(
    const float* __restrict__ x, const float* __restrict__ Wenc,
    float* __restrict__ partialT)
{
    __shared__ __align__(16) unsigned short wH[96 * WPITCH];  // 7.5 KB
    __shared__ __align__(16) unsigned short wL[96 * WPITCH];  // 7.5 KB

    const int tid  = threadIdx.x;
    const int lane = tid & 63;
    const int wv   = tid >> 6;          // 0..7
    const int ln15 = lane & 15;
    const int lg   = lane >> 4;         // 0..3
    const int m0   = wv << 4;
    const int kblk = blockIdx.x * KC;
    const float* __restrict__ xrow = x + (size_t)(m0 + ln15) * HW + kblk;

    f32x4 acc[6];
#pragma unroll
    for (int t = 0; t < 6; ++t) acc[t] = (f32x4){0.f, 0.f, 0.f, 0.f};

    float4 xa = *reinterpret_cast<const float4*>(&xrow[lg * 4]);
    float4 xb = *reinterpret_cast<const float4*>(&xrow[16 + lg * 4]);

    for (int step = 0; step < NSTEP; ++step) {
        __syncthreads();
        {
            const float4* wsrc = reinterpret_cast<const float4*>(
                Wenc + (size_t)(kblk + step * 32) * NF);
            for (int i4 = tid; i4 < (32 * NF) / 4; i4 += 512) {
                const float4 w4 = wsrc[i4];
                const float wv4[4] = {w4.x, w4.y, w4.z, w4.w};
#pragma unroll
                for (int j = 0; j < 4; ++j) {
                    const int idx = i4 * 4 + j;
                    const int kk  = idx / NF;
                    const int n   = idx - kk * NF;
                    const unsigned short hi = bf16rn(wv4[j]);
                    wH[n * WPITCH + kk] = hi;
                    wL[n * WPITCH + kk] = bf16rn(wv4[j] - bf16tof(hi));
                }
            }
        }
        float4 xa1, xb1;
        if (step + 1 < NSTEP) {
            xa1 = *reinterpret_cast<const float4*>(&xrow[(step + 1) * 32 + lg * 4]);
            xb1 = *reinterpret_cast<const float4*>(&xrow[(step + 1) * 32 + 16 + lg * 4]);
        }
        __syncthreads();

        s16x4 bh[2], bl[2];
        {
            const float xv[8] = {xa.x, xa.y, xa.z, xa.w, xb.x, xb.y, xb.z, xb.w};
#pragma unroll
            for (int s = 0; s < 2; ++s)
#pragma unroll
                for (int j = 0; j < 4; ++j) {
                    const float v = xv[s * 4 + j];
                    const unsigned short hi = bf16rn(v);
                    bh[s][j] = (short)hi;
                    bl[s][j] = (short)bf16rn(v - bf16tof(hi));
                }
        }

#pragma unroll
        for (int s = 0; s < 2; ++s) {
#pragma unroll
            for (int t = 0; t < 6; ++t) {
                const int aoff = (t * 16 + ln15) * WPITCH + s * 16 + lg * 4;
                const s16x4 ah = *reinterpret_cast<const s16x4*>(&wH[aoff]);
                acc[t] = __builtin_amdgcn_mfma_f32_16x16x16bf16_1k(
                    ah, bh[s], acc[t], 0, 0, 0);
                if (t >= 4) {   // theta tiles: 3-term bf16 split
                    const s16x4 al = *reinterpret_cast<const s16x4*>(&wL[aoff]);
                    acc[t] = __builtin_amdgcn_mfma_f32_16x16x16bf16_1k(
                        ah, bl[s], acc[t], 0, 0, 0);
                    acc[t] = __builtin_amdgcn_mfma_f32_16x16x16bf16_1k(
                        al, bh[s], acc[t], 0, 0, 0);
                }
            }
        }
        if (step + 1 < NSTEP) { xa = xa1; xb = xb1; }
    }

    float* __restrict__ base = partialT + (size_t)blockIdx.x * BNF;
#pragma unroll
    for (int t = 0; t < 5; ++t)
#pragma unroll
        for (int r = 0; r < 4; ++r) {
            const int n = t * 16 + lg * 4 + r;
            base[(size_t)n * B_ + m0 + ln15] = acc[t][r];
        }
    if (lg == 0) {
#pragma unroll
        for (int r = 0; r < 2; ++r)
            base[(size_t)(80 + r) * B_ + m0 + ln15] = acc[5][r];
    }
}

// ---------------- Encoder reduce: 256 -> 1 (+bias) ----------------
__global__ __launch_bounds__(1024) void enc_reduce(
    const float* __restrict__ partialT, const float* __restrict__ benc,
    float* __restrict__ featsT)
{
    __shared__ float red[8][128];
    const int n = blockIdx.x;
    const int m = threadIdx.x & 127;
    const int g = threadIdx.x >> 7;      // 0..7
    const float* p = partialT + (size_t)(g * 32) * BNF + (size_t)n * B_ + m;
    float s = 0.f;
#pragma unroll 8
    for (int c = 0; c < 32; ++c) s += p[(size_t)c * BNF];
    red[g][m] = s;
    __syncthreads();
    if (g == 0) {
        float t = benc[n];
#pragma unroll
        for (int j = 0; j < 8; ++j) t += red[j][m];
        featsT[(size_t)n * B_ + m] = t;
    }
}

// ---------------- Decoder GEMM: pred = emb @ W_dec + b_dec (bf16 out) -------
__global__ __launch_bounds__(512) void decoder_k(
    const float* __restrict__ featsT, const float* __restrict__ Wdec,
    const float* __restrict__ bdec, unsigned short* __restrict__ pred)
{
    __shared__ float embT[EMB_ * B_];   // 32 KB, [k*128+m]
    const int tid = threadIdx.x;
    for (int i = tid; i < EMB_ * B_; i += 512) embT[i] = featsT[i];
    __syncthreads();

    const int tp = tid & 15;
    const int tm = tid >> 4;                 // 0..31
    const int p0 = blockIdx.x * 64 + tp * 4;
    const int m0 = tm * 4;

    float acc[4][4];
#pragma unroll
    for (int i = 0; i < 4; ++i)
#pragma unroll
        for (int q = 0; q < 4; ++q) acc[i][q] = 0.f;

#pragma unroll 4
    for (int k = 0; k < EMB_; ++k) {
        const float4 w = *reinterpret_cast<const float4*>(&Wdec[(size_t)k * HW + p0]);
        float e[4];
#pragma unroll
        for (int i = 0; i < 4; ++i) e[i] = embT[k * B_ + m0 + i];
#pragma unroll
        for (int i = 0; i < 4; ++i) {
            acc[i][0] = fmaf(e[i], w.x, acc[i][0]);
            acc[i][1] = fmaf(e[i], w.y, acc[i][1]);
            acc[i][2] = fmaf(e[i], w.z, acc[i][2]);
            acc[i][3] = fmaf(e[i], w.w, acc[i][3]);
        }
    }
    const float4 bd = *reinterpret_cast<const float4*>(&bdec[p0]);
#pragma unroll
    for (int i = 0; i < 4; ++i) {
        ushort4 o;
        o.x = bf16rn(acc[i][0] + bd.x);
        o.y = bf16rn(acc[i][1] + bd.y);
        o.z = bf16rn(acc[i][2] + bd.z);
        o.w = bf16rn(acc[i][3] + bd.w);
        *reinterpret_cast<ushort4*>(&pred[(size_t)(m0 + i) * HW + p0]) = o;
    }
}

// ---------------- Grid-sample: zero-padded LDS image, branch-free taps -------
// 256 blocks x 1024 thr; block = one output half-image. Full 256x256 bf16
// source staged at rows 2..257 / cols 0..255 of a 260x260 LDS array whose
// border rows/cols (and a 4-short front slack) are zeroed. Clamping ix0,iy0
// to [-2,256] makes EVERY tap a plain ds_read_u16 (pads reproduce valid?v:0),
// eliminating all per-tap compare/select VALU. Per-thread x is constant and
// y steps by 4/iter, so coords are 2 fma/px from a hoisted base.
template <typename TO>
__global__ __launch_bounds__(1024) void gsample_pad(
    const unsigned short* __restrict__ src, TO* __restrict__ dst,
    const float* __restrict__ featsT, int theta_sel)
{
    extern __shared__ __align__(16) unsigned short sbase[];
    unsigned short* simg = sbase + 4;          // front slack handles o = -1, -2

    const int p    = blockIdx.x;
    const int b    = ((p >> 4) << 3) | (p & 7);   // pair halves onto one image
    const int half = (p >> 3) & 1;
    const int tid  = threadIdx.x;

    // zero the pads
    if (tid < 4) sbase[tid] = 0;
    for (int z = tid; z < 520; z += 1024) {      // rows 0,1 and 258,259
        simg[z] = 0;
        simg[258 * IPITCH + z] = 0;
    }
    if (tid < 256) {                              // cols 256..259, rows 2..257
        ushort4 zz; zz.x = zz.y = zz.z = zz.w = 0;
        *reinterpret_cast<ushort4*>(&simg[(tid + 2) * IPITCH + 256]) = zz;
    }
    // stage image rows 0..255 -> LDS rows 2..257 (coalesced ushort4)
    {
        const ushort4* __restrict__ s4 =
            reinterpret_cast<const ushort4*>(src + ((size_t)b << 16));
#pragma unroll
        for (int it = 0; it < 16; ++it) {
            const int i  = tid + (it << 10);
            const int r  = i >> 6;
            const int c4 = i & 63;
            *reinterpret_cast<ushort4*>(&simg[(r + 2) * IPITCH + (c4 << 2)]) = s4[i];
        }
    }

    const int tb = EMB_ + theta_sel * 6;
    const float t00 = featsT[(size_t)(tb + 0) * B_ + b];
    const float t01 = featsT[(size_t)(tb + 1) * B_ + b];
    const float t02 = featsT[(size_t)(tb + 2) * B_ + b];
    const float t10 = featsT[(size_t)(tb + 3) * B_ + b];
    const float t11 = featsT[(size_t)(tb + 4) * B_ + b];
    const float t12 = featsT[(size_t)(tb + 5) * B_ + b];

    // hoisted coordinate bases: x constant per thread, y = y0 + 4*it
    const float X  = (float)(2 * (tid & 255) + 1) * (1.f / 256.f) - 1.f;
    const int   y0 = (half << 7) + (tid >> 8);
    const float Y0 = (float)(2 * y0 + 1) * (1.f / 256.f) - 1.f;
    const float ixb = (t00 * X + t01 * Y0 + t02 + 1.f) * 128.f - 0.5f;
    const float iyb = (t10 * X + t11 * Y0 + t12 + 1.f) * 128.f - 0.5f;
    const float dix = 4.f * t01;
    const float diy = 4.f * t11;

    __syncthreads();

    TO* __restrict__ db = dst + ((size_t)b << 16) + ((size_t)half << 15) + tid;
    float fit = 0.f;
#pragma unroll 8
    for (int it = 0; it < 32; ++it) {
        const float ix = fmaf(fit, dix, ixb);
        const float iy = fmaf(fit, diy, iyb);
        fit += 1.f;
        const float ix0 = floorf(ix);
        const float iy0 = floorf(iy);
        const float wx1 = ix - ix0, wx0 = 1.f - wx1;
        const float wy1 = iy - iy0, wy0 = 1.f - wy1;
        const int xi  = (int)fminf(fmaxf(ix0, -2.f), 256.f);
        const int yi2 = (int)fminf(fmaxf(iy0, -2.f), 256.f) + 2;
        const int o = yi2 * IPITCH + xi;            // o >= -2: slack covers it
        const float v00 = bf16tof(simg[o]);
        const float v10 = bf16tof(simg[o + 1]);
        const float v01 = bf16tof(simg[o + IPITCH]);
        const float v11 = bf16tof(simg[o + IPITCH + 1]);
        const float r = wy0 * fmaf(wx1, v10, wx0 * v00) +
                        wy1 * fmaf(wx1, v11, wx0 * v01);
        stpix(db + (it << 10), r);
    }
}

extern "C" void kernel_launch(void* const* d_in, const int* in_sizes, int n_in,
                              void* d_out, int out_size, void* d_ws, size_t ws_size,
                              hipStream_t stream)
{
    const float* x    = (const float*)d_in[0];
    const float* Wenc = (const float*)d_in[1];
    const float* benc = (const float*)d_in[2];
    const float* Wdec = (const float*)d_in[3];
    const float* bdec = (const float*)d_in[4];
    float* out = (float*)d_out;

    char* wsb = (char*)d_ws;
    float* partialT       = (float*)wsb;                          // 10.7 MB (dead after enc_reduce)
    unsigned short* imgB0 = (unsigned short*)wsb;                 // 16.7 MB (written after partialT dead)
    unsigned short* imgB1 = (unsigned short*)(wsb + (20u << 20)); // 16.7 MB
    float* featsT         = (float*)(wsb + (40u << 20));          // 41 KB

    (void)hipFuncSetAttribute((const void*)gsample_pad<unsigned short>,
        hipFuncAttributeMaxDynamicSharedMemorySize, (int)GS_LDS);
    (void)hipFuncSetAttribute((const void*)gsample_pad<float>,
        hipFuncAttributeMaxDynamicSharedMemorySize, (int)GS_LDS);

    enc_mfma_k<<<KCH, 512, 0, stream>>>(x, Wenc, partialT);
    enc_reduce<<<NF, 1024, 0, stream>>>(partialT, benc, featsT);
    decoder_k<<<1024, 512, 0, stream>>>(featsT, Wdec, bdec, imgB0);
    // reference order: grid_3 (translation=2), grid_1 (scaler_shear=0), grid_2 (rotation=1)
    gsample_pad<unsigned short><<<256, 1024, GS_LDS, stream>>>(imgB0, imgB1, featsT, 2);
    gsample_pad<unsigned short><<<256, 1024, GS_LDS, stream>>>(imgB1, imgB0, featsT, 0);
    gsample_pad<float>         <<<256, 1024, GS_LDS, stream>>>(imgB0, out,  featsT, 1);
}

// Round 11
// 147.785 us; speedup vs baseline: 4.9583x; 1.0009x over previous
//
#include <hip/hip_runtime.h>
#include <cstddef>

namespace {
constexpr int B_   = 128;
constexpr int HW   = 65536;        // 256*256
constexpr int EMB_ = 64;
constexpr int NF   = EMB_ + 18;    // 82
constexpr int BNF  = B_ * NF;      // 10496  ([n][m] layout)
constexpr int KCH  = 256;          // k-chunks (encoder grid)
constexpr int KC   = HW / KCH;     // 256 k per block
constexpr int NSTEP = KC / 32;     // 8 steps of 32 k
constexpr int WPITCH = 40;         // W tile row pitch in bf16 (32 + 8 pad)
constexpr int IPITCH = 260;        // LDS image row pitch in bf16
// padded image: 4-short front slack + 260 rows (image at rows 2..257, cols 0..255;
// rows 0,1,258,259 and cols 256..259 zeroed -> taps need no validity logic)
constexpr int SIMG_SHORTS = 4 + 260 * IPITCH;
constexpr size_t GS_LDS = (size_t)SIMG_SHORTS * 2 + 8;   // 135216 B
}

typedef short  s16x4 __attribute__((ext_vector_type(4)));
typedef float  f32x4 __attribute__((ext_vector_type(4)));

__device__ __forceinline__ unsigned short bf16rn(float f) {
    unsigned u = __float_as_uint(f);
    u += 0x7FFFu + ((u >> 16) & 1u);
    return (unsigned short)(u >> 16);
}
__device__ __forceinline__ float bf16tof(unsigned short h) {
    return __uint_as_float(((unsigned)h) << 16);
}
__device__ __forceinline__ void stpix(unsigned short* p, float v) { *p = bf16rn(v); }
__device__ __forceinline__ void stpix(float* p, float v)          { *p = v; }

// ---------------- Encoder: split-K bf16 MFMA ----------------
__global__ __launch_bounds__(512) void enc_mfma_k(
    const float* __restrict__ x, const float* __restrict__ Wenc,
    float* __restrict__ partialT)
{
    __shared__ __align__(16) unsigned short wH[96 * WPITCH];  // 7.5 KB
    __shared__ __align__(16) unsigned short wL[96 * WPITCH];  // 7.5 KB

    const int tid  = threadIdx.x;
    const int lane = tid & 63;
    const int wv   = tid >> 6;          // 0..7
    const int ln15 = lane & 15;
    const int lg   = lane >> 4;         // 0..3
    const int m0   = wv << 4;
    const int kblk = blockIdx.x * KC;
    const float* __restrict__ xrow = x + (size_t)(m0 + ln15) * HW + kblk;

    f32x4 acc[6];
#pragma unroll
    for (int t = 0; t < 6; ++t) acc[t] = (f32x4){0.f, 0.f, 0.f, 0.f};

    float4 xa = *reinterpret_cast<const float4*>(&xrow[lg * 4]);
    float4 xb = *reinterpret_cast<const float4*>(&xrow[16 + lg * 4]);

    for (int step = 0; step < NSTEP; ++step) {
        __syncthreads();
        {
            const float4* wsrc = reinterpret_cast<const float4*>(
                Wenc + (size_t)(kblk + step * 32) * NF);
            for (int i4 = tid; i4 < (32 * NF) / 4; i4 += 512) {
                const float4 w4 = wsrc[i4];
                const float wv4[4] = {w4.x, w4.y, w4.z, w4.w};
#pragma unroll
                for (int j = 0; j < 4; ++j) {
                    const int idx = i4 * 4 + j;
                    const int kk  = idx / NF;
                    const int n   = idx - kk * NF;
                    const unsigned short hi = bf16rn(wv4[j]);
                    wH[n * WPITCH + kk] = hi;
                    wL[n * WPITCH + kk] = bf16rn(wv4[j] - bf16tof(hi));
                }
            }
        }
        float4 xa1, xb1;
        if (step + 1 < NSTEP) {
            xa1 = *reinterpret_cast<const float4*>(&xrow[(step + 1) * 32 + lg * 4]);
            xb1 = *reinterpret_cast<const float4*>(&xrow[(step + 1) * 32 + 16 + lg * 4]);
        }
        __syncthreads();

        s16x4 bh[2], bl[2];
        {
            const float xv[8] = {xa.x, xa.y, xa.z, xa.w, xb.x, xb.y, xb.z, xb.w};
#pragma unroll
            for (int s = 0; s < 2; ++s)
#pragma unroll
                for (int j = 0; j < 4; ++j) {
                    const float v = xv[s * 4 + j];
                    const unsigned short hi = bf16rn(v);
                    bh[s][j] = (short)hi;
                    bl[s][j] = (short)bf16rn(v - bf16tof(hi));
                }
        }

#pragma unroll
        for (int s = 0; s < 2; ++s) {
#pragma unroll
            for (int t = 0; t < 6; ++t) {
                const int aoff = (t * 16 + ln15) * WPITCH + s * 16 + lg * 4;
                const s16x4 ah = *reinterpret_cast<const s16x4*>(&wH[aoff]);
                acc[t] = __builtin_amdgcn_mfma_f32_16x16x16bf16_1k(
                    ah, bh[s], acc[t], 0, 0, 0);
                if (t >= 4) {   // theta tiles: 3-term bf16 split
                    const s16x4 al = *reinterpret_cast<const s16x4*>(&wL[aoff]);
                    acc[t] = __builtin_amdgcn_mfma_f32_16x16x16bf16_1k(
                        ah, bl[s], acc[t], 0, 0, 0);
                    acc[t] = __builtin_amdgcn_mfma_f32_16x16x16bf16_1k(
                        al, bh[s], acc[t], 0, 0, 0);
                }
            }
        }
        if (step + 1 < NSTEP) { xa = xa1; xb = xb1; }
    }

    float* __restrict__ base = partialT + (size_t)blockIdx.x * BNF;
#pragma unroll
    for (int t = 0; t < 5; ++t)
#pragma unroll
        for (int r = 0; r < 4; ++r) {
            const int n = t * 16 + lg * 4 + r;
            base[(size_t)n * B_ + m0 + ln15] = acc[t][r];
        }
    if (lg == 0) {
#pragma unroll
        for (int r = 0; r < 2; ++r)
            base[(size_t)(80 + r) * B_ + m0 + ln15] = acc[5][r];
    }
}

// ---------------- Encoder reduce: 256 -> 1 (+bias) ----------------
__global__ __launch_bounds__(1024) void enc_reduce(
    const float* __restrict__ partialT, const float* __restrict__ benc,
    float* __restrict__ featsT)
{
    __shared__ float red[8][128];
    const int n = blockIdx.x;
    const int m = threadIdx.x & 127;
    const int g = threadIdx.x >> 7;      // 0..7
    const float* p = partialT + (size_t)(g * 32) * BNF + (size_t)n * B_ + m;
    float s = 0.f;
#pragma unroll 8
    for (int c = 0; c < 32; ++c) s += p[(size_t)c * BNF];
    red[g][m] = s;
    __syncthreads();
    if (g == 0) {
        float t = benc[n];
#pragma unroll
        for (int j = 0; j < 8; ++j) t += red[j][m];
        featsT[(size_t)n * B_ + m] = t;
    }
}

// ---------------- Decoder GEMM: pred = emb @ W_dec + b_dec (bf16 out) -------
__global__ __launch_bounds__(512) void decoder_k(
    const float* __restrict__ featsT, const float* __restrict__ Wdec,
    const float* __restrict__ bdec, unsigned short* __restrict__ pred)
{
    __shared__ float embT[EMB_ * B_];   // 32 KB, [k*128+m]
    const int tid = threadIdx.x;
    for (int i = tid; i < EMB_ * B_; i += 512) embT[i] = featsT[i];
    __syncthreads();

    const int tp = tid & 15;
    const int tm = tid >> 4;                 // 0..31
    const int p0 = blockIdx.x * 64 + tp * 4;
    const int m0 = tm * 4;

    float acc[4][4];
#pragma unroll
    for (int i = 0; i < 4; ++i)
#pragma unroll
        for (int q = 0; q < 4; ++q) acc[i][q] = 0.f;

#pragma unroll 4
    for (int k = 0; k < EMB_; ++k) {
        const float4 w = *reinterpret_cast<const float4*>(&Wdec[(size_t)k * HW + p0]);
        float e[4];
#pragma unroll
        for (int i = 0; i < 4; ++i) e[i] = embT[k * B_ + m0 + i];
#pragma unroll
        for (int i = 0; i < 4; ++i) {
            acc[i][0] = fmaf(e[i], w.x, acc[i][0]);
            acc[i][1] = fmaf(e[i], w.y, acc[i][1]);
            acc[i][2] = fmaf(e[i], w.z, acc[i][2]);
            acc[i][3] = fmaf(e[i], w.w, acc[i][3]);
        }
    }
    const float4 bd = *reinterpret_cast<const float4*>(&bdec[p0]);
#pragma unroll
    for (int i = 0; i < 4; ++i) {
        ushort4 o;
        o.x = bf16rn(acc[i][0] + bd.x);
        o.y = bf16rn(acc[i][1] + bd.y);
        o.z = bf16rn(acc[i][2] + bd.z);
        o.w = bf16rn(acc[i][3] + bd.w);
        *reinterpret_cast<ushort4*>(&pred[(size_t)(m0 + i) * HW + p0]) = o;
    }
}

// ---------------- Grid-sample: zero-padded LDS image, branch-free taps -------
// 256 blocks x 1024 thr; block = one output half-image. Full source staged at
// rows 2..257 / cols 0..255 of a 260x260 LDS array; border rows/cols + front
// slack zeroed, so every tap is a plain ds_read_u16 (pads reproduce valid?v:0).
// Coordinates: x constant per thread, y steps 4/iter -> 2 fma/px.
// CRITICAL: unroll stays at 2. 1024-thread WG => hard 128-VGPR cap (16 waves
// must co-reside); unroll 8 spilled to scratch and cost +14 us/phase (round 10).
template <typename TO>
__global__ __launch_bounds__(1024) void gsample_pad(
    const unsigned short* __restrict__ src, TO* __restrict__ dst,
    const float* __restrict__ featsT, int theta_sel)
{
    extern __shared__ __align__(16) unsigned short sbase[];
    unsigned short* simg = sbase + 4;          // front slack covers o = -1, -2

    const int p    = blockIdx.x;
    const int b    = ((p >> 4) << 3) | (p & 7);   // pair halves onto one image
    const int half = (p >> 3) & 1;
    const int tid  = threadIdx.x;

    // zero the pads
    if (tid < 4) sbase[tid] = 0;
    for (int z = tid; z < 520; z += 1024) {      // rows 0,1 and 258,259
        simg[z] = 0;
        simg[258 * IPITCH + z] = 0;
    }
    if (tid < 256) {                              // cols 256..259, rows 2..257
        ushort4 zz; zz.x = zz.y = zz.z = zz.w = 0;
        *reinterpret_cast<ushort4*>(&simg[(tid + 2) * IPITCH + 256]) = zz;
    }
    // stage image rows 0..255 -> LDS rows 2..257 (coalesced ushort4)
    {
        const ushort4* __restrict__ s4 =
            reinterpret_cast<const ushort4*>(src + ((size_t)b << 16));
#pragma unroll
        for (int it = 0; it < 16; ++it) {
            const int i  = tid + (it << 10);
            const int r  = i >> 6;
            const int c4 = i & 63;
            *reinterpret_cast<ushort4*>(&simg[(r + 2) * IPITCH + (c4 << 2)]) = s4[i];
        }
    }

    const int tb = EMB_ + theta_sel * 6;
    const float t00 = featsT[(size_t)(tb + 0) * B_ + b];
    const float t01 = featsT[(size_t)(tb + 1) * B_ + b];
    const float t02 = featsT[(size_t)(tb + 2) * B_ + b];
    const float t10 = featsT[(size_t)(tb + 3) * B_ + b];
    const float t11 = featsT[(size_t)(tb + 4) * B_ + b];
    const float t12 = featsT[(size_t)(tb + 5) * B_ + b];

    // hoisted coordinate bases: x constant per thread, y = y0 + 4*it
    const float X  = (float)(2 * (tid & 255) + 1) * (1.f / 256.f) - 1.f;
    const int   y0 = (half << 7) + (tid >> 8);
    const float Y0 = (float)(2 * y0 + 1) * (1.f / 256.f) - 1.f;
    const float ixb = (t00 * X + t01 * Y0 + t02 + 1.f) * 128.f - 0.5f;
    const float iyb = (t10 * X + t11 * Y0 + t12 + 1.f) * 128.f - 0.5f;
    const float dix = 4.f * t01;
    const float diy = 4.f * t11;

    __syncthreads();

    TO* __restrict__ db = dst + ((size_t)b << 16) + ((size_t)half << 15) + tid;
    float fit = 0.f;
#pragma unroll 2
    for (int it = 0; it < 32; ++it) {
        const float ix = fmaf(fit, dix, ixb);
        const float iy = fmaf(fit, diy, iyb);
        fit += 1.f;
        const float ix0 = floorf(ix);
        const float iy0 = floorf(iy);
        const float wx1 = ix - ix0, wx0 = 1.f - wx1;
        const float wy1 = iy - iy0, wy0 = 1.f - wy1;
        const int xi  = (int)fminf(fmaxf(ix0, -2.f), 256.f);
        const int yi2 = (int)fminf(fmaxf(iy0, -2.f), 256.f) + 2;
        const int o = yi2 * IPITCH + xi;            // o >= -2: slack covers it
        const float v00 = bf16tof(simg[o]);
        const float v10 = bf16tof(simg[o + 1]);
        const float v01 = bf16tof(simg[o + IPITCH]);
        const float v11 = bf16tof(simg[o + IPITCH + 1]);
        const float r = wy0 * fmaf(wx1, v10, wx0 * v00) +
                        wy1 * fmaf(wx1, v11, wx0 * v01);
        stpix(db + (it << 10), r);
    }
}

extern "C" void kernel_launch(void* const* d_in, const int* in_sizes, int n_in,
                              void* d_out, int out_size, void* d_ws, size_t ws_size,
                              hipStream_t stream)
{
    const float* x    = (const float*)d_in[0];
    const float* Wenc = (const float*)d_in[1];
    const float* benc = (const float*)d_in[2];
    const float* Wdec = (const float*)d_in[3];
    const float* bdec = (const float*)d_in[4];
    float* out = (float*)d_out;

    char* wsb = (char*)d_ws;
    float* partialT       = (float*)wsb;                          // 10.7 MB (dead after enc_reduce)
    unsigned short* imgB0 = (unsigned short*)wsb;                 // 16.7 MB (written after partialT dead)
    unsigned short* imgB1 = (unsigned short*)(wsb + (20u << 20)); // 16.7 MB
    float* featsT         = (float*)(wsb + (40u << 20));          // 41 KB

    (void)hipFuncSetAttribute((const void*)gsample_pad<unsigned short>,
        hipFuncAttributeMaxDynamicSharedMemorySize, (int)GS_LDS);
    (void)hipFuncSetAttribute((const void*)gsample_pad<float>,
        hipFuncAttributeMaxDynamicSharedMemorySize, (int)GS_LDS);

    enc_mfma_k<<<KCH, 512, 0, stream>>>(x, Wenc, partialT);
    enc_reduce<<<NF, 1024, 0, stream>>>(partialT, benc, featsT);
    decoder_k<<<1024, 512, 0, stream>>>(featsT, Wdec, bdec, imgB0);
    // reference order: grid_3 (translation=2), grid_1 (scaler_shear=0), grid_2 (rotation=1)
    gsample_pad<unsigned short><<<256, 1024, GS_LDS, stream>>>(imgB0, imgB1, featsT, 2);
    gsample_pad<unsigned short><<<256, 1024, GS_LDS, stream>>>(imgB1, imgB0, featsT, 0);
    gsample_pad<float>         <<<256, 1024, GS_LDS, stream>>>(imgB0, out,  featsT, 1);
}

// Round 12
// 106.276 us; speedup vs baseline: 6.8950x; 1.3906x over previous
//
#include <hip/hip_runtime.h>
#include <cstddef>

namespace {
constexpr int B_   = 128;
constexpr int HW   = 65536;        // 256*256
constexpr int EMB_ = 64;
constexpr int NF   = EMB_ + 18;    // 82
constexpr int BNF  = B_ * NF;      // 10496  ([n][m] layout)
constexpr int KCH  = 256;          // k-chunks (encoder grid)
constexpr int KC   = HW / KCH;     // 256 k per block
constexpr int NSTEP = KC / 32;     // 8 steps of 32 k
constexpr int WPITCH = 40;         // W tile row pitch in bf16 (32 + 8 pad)
constexpr int IPITCH = 260;        // LDS image row pitch in bf16
constexpr size_t GS_LDS = (size_t)256 * IPITCH * 2;  // 133120 B (round-8 exact)
}

typedef short  s16x4 __attribute__((ext_vector_type(4)));
typedef float  f32x4 __attribute__((ext_vector_type(4)));

__device__ __forceinline__ unsigned short bf16rn(float f) {
    unsigned u = __float_as_uint(f);
    u += 0x7FFFu + ((u >> 16) & 1u);
    return (unsigned short)(u >> 16);
}
__device__ __forceinline__ float bf16tof(unsigned short h) {
    return __uint_as_float(((unsigned)h) << 16);
}
__device__ __forceinline__ void stpix(unsigned short* p, float v) { *p = bf16rn(v); }
__device__ __forceinline__ void stpix(float* p, float v)          { *p = v; }

// ---------------- Encoder: split-K bf16 MFMA (round-8 exact) ----------------
__global__ __launch_bounds__(512) void enc_mfma_k(
    const float* __restrict__ x, const float* __restrict__ Wenc,
    float* __restrict__ partialT)
{
    __shared__ __align__(16) unsigned short wH[96 * WPITCH];  // 7.5 KB
    __shared__ __align__(16) unsigned short wL[96 * WPITCH];  // 7.5 KB

    const int tid  = threadIdx.x;
    const int lane = tid & 63;
    const int wv   = tid >> 6;          // 0..7
    const int ln15 = lane & 15;
    const int lg   = lane >> 4;         // 0..3
    const int m0   = wv << 4;
    const int kblk = blockIdx.x * KC;
    const float* __restrict__ xrow = x + (size_t)(m0 + ln15) * HW + kblk;

    f32x4 acc[6];
#pragma unroll
    for (int t = 0; t < 6; ++t) acc[t] = (f32x4){0.f, 0.f, 0.f, 0.f};

    float4 xa = *reinterpret_cast<const float4*>(&xrow[lg * 4]);
    float4 xb = *reinterpret_cast<const float4*>(&xrow[16 + lg * 4]);

    for (int step = 0; step < NSTEP; ++step) {
        __syncthreads();
        {
            const float4* wsrc = reinterpret_cast<const float4*>(
                Wenc + (size_t)(kblk + step * 32) * NF);
            for (int i4 = tid; i4 < (32 * NF) / 4; i4 += 512) {
                const float4 w4 = wsrc[i4];
                const float wv4[4] = {w4.x, w4.y, w4.z, w4.w};
#pragma unroll
                for (int j = 0; j < 4; ++j) {
                    const int idx = i4 * 4 + j;
                    const int kk  = idx / NF;
                    const int n   = idx - kk * NF;
                    const unsigned short hi = bf16rn(wv4[j]);
                    wH[n * WPITCH + kk] = hi;
                    wL[n * WPITCH + kk] = bf16rn(wv4[j] - bf16tof(hi));
                }
            }
        }
        float4 xa1, xb1;
        if (step + 1 < NSTEP) {
            xa1 = *reinterpret_cast<const float4*>(&xrow[(step + 1) * 32 + lg * 4]);
            xb1 = *reinterpret_cast<const float4*>(&xrow[(step + 1) * 32 + 16 + lg * 4]);
        }
        __syncthreads();

        s16x4 bh[2], bl[2];
        {
            const float xv[8] = {xa.x, xa.y, xa.z, xa.w, xb.x, xb.y, xb.z, xb.w};
#pragma unroll
            for (int s = 0; s < 2; ++s)
#pragma unroll
                for (int j = 0; j < 4; ++j) {
                    const float v = xv[s * 4 + j];
                    const unsigned short hi = bf16rn(v);
                    bh[s][j] = (short)hi;
                    bl[s][j] = (short)bf16rn(v - bf16tof(hi));
                }
        }

#pragma unroll
        for (int s = 0; s < 2; ++s) {
#pragma unroll
            for (int t = 0; t < 6; ++t) {
                const int aoff = (t * 16 + ln15) * WPITCH + s * 16 + lg * 4;
                const s16x4 ah = *reinterpret_cast<const s16x4*>(&wH[aoff]);
                acc[t] = __builtin_amdgcn_mfma_f32_16x16x16bf16_1k(
                    ah, bh[s], acc[t], 0, 0, 0);
                if (t >= 4) {   // theta tiles: 3-term bf16 split
                    const s16x4 al = *reinterpret_cast<const s16x4*>(&wL[aoff]);
                    acc[t] = __builtin_amdgcn_mfma_f32_16x16x16bf16_1k(
                        ah, bl[s], acc[t], 0, 0, 0);
                    acc[t] = __builtin_amdgcn_mfma_f32_16x16x16bf16_1k(
                        al, bh[s], acc[t], 0, 0, 0);
                }
            }
        }
        if (step + 1 < NSTEP) { xa = xa1; xb = xb1; }
    }

    float* __restrict__ base = partialT + (size_t)blockIdx.x * BNF;
#pragma unroll
    for (int t = 0; t < 5; ++t)
#pragma unroll
        for (int r = 0; r < 4; ++r) {
            const int n = t * 16 + lg * 4 + r;
            base[(size_t)n * B_ + m0 + ln15] = acc[t][r];
        }
    if (lg == 0) {
#pragma unroll
        for (int r = 0; r < 2; ++r)
            base[(size_t)(80 + r) * B_ + m0 + ln15] = acc[5][r];
    }
}

// ---------------- Encoder reduce: 256 -> 1 (+bias), widened to 164 blocks ----
// grid (82, 2): block = (feature row n, m-half). Same summation order per
// element as before: 32-chunk serial per group, 8-group tree.
__global__ __launch_bounds__(512) void enc_reduce(
    const float* __restrict__ partialT, const float* __restrict__ benc,
    float* __restrict__ featsT)
{
    __shared__ float red[8][64];
    const int n  = blockIdx.x;
    const int ml = threadIdx.x & 63;
    const int m  = (blockIdx.y << 6) + ml;
    const int g  = threadIdx.x >> 6;     // 0..7
    const float* p = partialT + (size_t)(g * 32) * BNF + (size_t)n * B_ + m;
    float s = 0.f;
#pragma unroll 8
    for (int c = 0; c < 32; ++c) s += p[(size_t)c * BNF];
    red[g][ml] = s;
    __syncthreads();
    if (g == 0) {
        float t = benc[n];
#pragma unroll
        for (int j = 0; j < 8; ++j) t += red[j][ml];
        featsT[(size_t)n * B_ + m] = t;
    }
}

// ------------- Decoder GEMM (round-8 exact): bf16 out, Wdec read once -------
__global__ __launch_bounds__(512) void decoder_k(
    const float* __restrict__ featsT, const float* __restrict__ Wdec,
    const float* __restrict__ bdec, unsigned short* __restrict__ pred)
{
    __shared__ float embT[EMB_ * B_];   // 32 KB, [k*128+m]
    const int tid = threadIdx.x;
    for (int i = tid; i < EMB_ * B_; i += 512) embT[i] = featsT[i];
    __syncthreads();

    const int tp = tid & 15;
    const int tm = tid >> 4;                 // 0..31
    const int p0 = blockIdx.x * 64 + tp * 4;
    const int m0 = tm * 4;

    float acc[4][4];
#pragma unroll
    for (int i = 0; i < 4; ++i)
#pragma unroll
        for (int q = 0; q < 4; ++q) acc[i][q] = 0.f;

#pragma unroll 4
    for (int k = 0; k < EMB_; ++k) {
        const float4 w = *reinterpret_cast<const float4*>(&Wdec[(size_t)k * HW + p0]);
        float e[4];
#pragma unroll
        for (int i = 0; i < 4; ++i) e[i] = embT[k * B_ + m0 + i];
#pragma unroll
        for (int i = 0; i < 4; ++i) {
            acc[i][0] = fmaf(e[i], w.x, acc[i][0]);
            acc[i][1] = fmaf(e[i], w.y, acc[i][1]);
            acc[i][2] = fmaf(e[i], w.z, acc[i][2]);
            acc[i][3] = fmaf(e[i], w.w, acc[i][3]);
        }
    }
    const float4 bd = *reinterpret_cast<const float4*>(&bdec[p0]);
#pragma unroll
    for (int i = 0; i < 4; ++i) {
        ushort4 o;
        o.x = bf16rn(acc[i][0] + bd.x);
        o.y = bf16rn(acc[i][1] + bd.y);
        o.z = bf16rn(acc[i][2] + bd.z);
        o.w = bf16rn(acc[i][3] + bd.w);
        *reinterpret_cast<ushort4*>(&pred[(size_t)(m0 + i) * HW + p0]) = o;
    }
}

// ------ Grid-sample (ROUND-8 BYTE-EXACT): whole source image in LDS ---------
// 256 blocks x 1024 thr. Block = one output half-image; stages the FULL
// 256x256 bf16 source into LDS coalesced, taps as ds_read_u16 with
// clamp+select validity. This is the only variant measured at 106 us total;
// pad/hoist variants (r10/r11) measured +42 us — do not "improve" without
// per-dispatch evidence.
template <typename TO>
__global__ __launch_bounds__(1024) void gsample_lds(
    const unsigned short* __restrict__ src, TO* __restrict__ dst,
    const float* __restrict__ featsT, int theta_sel)
{
    extern __shared__ unsigned short simg[];   // [256][IPITCH]

    const int p    = blockIdx.x;
    const int b    = ((p >> 4) << 3) | (p & 7);
    const int half = (p >> 3) & 1;
    const int tid  = threadIdx.x;

    const unsigned short* __restrict__ sb = src + ((size_t)b << 16);
    {
        const ushort4* __restrict__ s4 = reinterpret_cast<const ushort4*>(sb);
#pragma unroll
        for (int it = 0; it < 16; ++it) {
            const int i = tid + (it << 10);
            const int r  = i >> 6;
            const int c4 = i & 63;
            *reinterpret_cast<ushort4*>(&simg[r * IPITCH + (c4 << 2)]) = s4[i];
        }
    }

    const int tb = EMB_ + theta_sel * 6;
    const float t00 = featsT[(size_t)(tb + 0) * B_ + b];
    const float t01 = featsT[(size_t)(tb + 1) * B_ + b];
    const float t02 = featsT[(size_t)(tb + 2) * B_ + b];
    const float t10 = featsT[(size_t)(tb + 3) * B_ + b];
    const float t11 = featsT[(size_t)(tb + 4) * B_ + b];
    const float t12 = featsT[(size_t)(tb + 5) * B_ + b];

    __syncthreads();

    TO* __restrict__ db = dst + ((size_t)b << 16) + ((size_t)half << 15);

#pragma unroll 2
    for (int it = 0; it < 32; ++it) {
        const int px = (it << 10) + tid;      // 0..32767 within half
        const int y  = (half << 7) + (px >> 8);
        const int xq = px & 255;

        const float X = (float)(2 * xq + 1) * (1.f / 256.f) - 1.f;
        const float Y = (float)(2 * y  + 1) * (1.f / 256.f) - 1.f;

        const float gx = t00 * X + t01 * Y + t02;
        const float gy = t10 * X + t11 * Y + t12;

        const float ix = (gx + 1.f) * 128.f - 0.5f;
        const float iy = (gy + 1.f) * 128.f - 0.5f;
        const float ix0 = floorf(ix);
        const float iy0 = floorf(iy);
        const float wx1 = ix - ix0, wx0 = 1.f - wx1;
        const float wy1 = iy - iy0, wy0 = 1.f - wy1;

        auto tap = [&](float xf, float yf) -> float {
            const bool valid = (xf >= 0.f) && (xf < 256.f) &&
                               (yf >= 0.f) && (yf < 256.f);
            const int xi = (int)fminf(fmaxf(xf, 0.f), 255.f);
            const int yi = (int)fminf(fmaxf(yf, 0.f), 255.f);
            const float v = bf16tof(simg[yi * IPITCH + xi]);
            return valid ? v : 0.f;
        };
        const float v00 = tap(ix0,       iy0);
        const float v10 = tap(ix0 + 1.f, iy0);
        const float v01 = tap(ix0,       iy0 + 1.f);
        const float v11 = tap(ix0 + 1.f, iy0 + 1.f);

        stpix(db + px,
              v00 * (wx0 * wy0) + v10 * (wx1 * wy0) +
              v01 * (wx0 * wy1) + v11 * (wx1 * wy1));
    }
}

extern "C" void kernel_launch(void* const* d_in, const int* in_sizes, int n_in,
                              void* d_out, int out_size, void* d_ws, size_t ws_size,
                              hipStream_t stream)
{
    const float* x    = (const float*)d_in[0];
    const float* Wenc = (const float*)d_in[1];
    const float* benc = (const float*)d_in[2];
    const float* Wdec = (const float*)d_in[3];
    const float* bdec = (const float*)d_in[4];
    float* out = (float*)d_out;

    char* wsb = (char*)d_ws;
    float* partialT       = (float*)wsb;                          // 10.7 MB (dead after enc_reduce)
    unsigned short* imgB0 = (unsigned short*)wsb;                 // 16.7 MB (written after partialT dead)
    unsigned short* imgB1 = (unsigned short*)(wsb + (20u << 20)); // 16.7 MB
    float* featsT         = (float*)(wsb + (40u << 20));          // 41 KB

    (void)hipFuncSetAttribute((const void*)gsample_lds<unsigned short>,
        hipFuncAttributeMaxDynamicSharedMemorySize, (int)GS_LDS);
    (void)hipFuncSetAttribute((const void*)gsample_lds<float>,
        hipFuncAttributeMaxDynamicSharedMemorySize, (int)GS_LDS);

    enc_mfma_k<<<KCH, 512, 0, stream>>>(x, Wenc, partialT);
    enc_reduce<<<dim3(NF, 2), 512, 0, stream>>>(partialT, benc, featsT);
    decoder_k<<<1024, 512, 0, stream>>>(featsT, Wdec, bdec, imgB0);
    // reference order: grid_3 (translation=2), grid_1 (scaler_shear=0), grid_2 (rotation=1)
    gsample_lds<unsigned short><<<256, 1024, GS_LDS, stream>>>(imgB0, imgB1, featsT, 2);
    gsample_lds<unsigned short><<<256, 1024, GS_LDS, stream>>>(imgB1, imgB0, featsT, 0);
    gsample_lds<float>         <<<256, 1024, GS_LDS, stream>>>(imgB0, out,  featsT, 1);
}